// Round 3
// baseline (353.230 us; speedup 1.0000x reference)
//
#include <hip/hip_runtime.h>

typedef unsigned int u32;

#define HW 3136

// workspace offsets (float units)
#define OFF_W7    0        // 128*49 combined dw weights (lepe BN folded)
#define OFF_BIAS  6272     // 128 folded lepe bias
#define OFF_POOL  6400     // 4*128*49
#define OFF_KEY   31488    // 4*128*49
#define OFF_AVG   56576    // 4*128 sum accumulators
#define OFF_MAXU  57088    // 4*128 max accumulators (encoded u32)
#define OFF_VALUE 57600    // 4*128*3136
#define OFF_GATE  1663232  // 4*128*3136
#define OFF_DYN   3268864  // 4*49*3136
#define OFF_XF    3883520  // 4*128*3136
// total: 5,489,152 floats = 21.96 MB

struct Params {
  const float *x_up, *x_skip, *wq, *bq, *wk, *bk, *wv, *bv, *ww, *bw;
  const float *lk_w, *lk_s, *lk_b, *dw5, *s5, *b5, *dw3a, *s3a, *b3a,
              *dw3b, *s3b, *b3b, *dw3c, *s3c, *b3c, *lepe_s, *lepe_b;
  const float *gate_w, *gate_s, *gate_b, *fus_w, *fus_b, *ca_w1, *ca_w2, *res;
  float* W;
  float* out;
};

__device__ __forceinline__ u32 fenc(float f){
  union{float f; u32 u;} v; v.f = f;
  return (v.u & 0x80000000u) ? ~v.u : (v.u | 0x80000000u);
}
__device__ __forceinline__ float fdec(u32 u){
  union{float f; u32 uu;} v;
  v.uu = (u & 0x80000000u) ? (u ^ 0x80000000u) : ~u;
  return v.f;
}

// ---------------------------------------------------------------------------
// K0: combined 7x7 dw weights (+folded BNs), pooled 7x7 (block mean of 8x8),
//     init channel-attention accumulators.
__global__ __launch_bounds__(256) void k_prep(Params P){
  float* W = P.W;
  const int tid = threadIdx.x, blk = blockIdx.x;
  if (blk < 32){
    const int b = blk >> 3, cg = blk & 7;
    for (int o = tid; o < 16*49; o += 256){
      const int c = cg*16 + o/49, l = o % 49;
      const int i = l/7, j = l%7;
      const float* src = P.x_up + (size_t)(b*128 + c)*HW + (i*8)*56 + j*8;
      float s = 0.f;
      #pragma unroll
      for (int di=0; di<8; ++di){
        const float4 a0 = *(const float4*)(src + di*56);
        const float4 a1 = *(const float4*)(src + di*56 + 4);
        s += a0.x+a0.y+a0.z+a0.w + a1.x+a1.y+a1.z+a1.w;
      }
      W[OFF_POOL + (size_t)(b*128+c)*49 + l] = s * (1.f/64.f);
    }
  } else {
    for (int idx = tid; idx < 128*49; idx += 256){
      const int c = idx/49, k = idx%49;
      const int dy = k/7 - 3, dx = k%7 - 3;
      float w = P.lk_s[c] * P.lk_w[c*49 + k];
      if (dy>=-2 && dy<=2 && dx>=-2 && dx<=2)
        w += P.s5[c] * P.dw5[c*25 + (dy+2)*5 + (dx+2)];
      if (dy>=-1 && dy<=1 && dx>=-1 && dx<=1)
        w += P.s3a[c] * P.dw3a[c*9 + (dy+1)*3 + (dx+1)];
      if ((dy==-2||dy==0||dy==2) && (dx==-2||dx==0||dx==2))
        w += P.s3b[c] * P.dw3b[c*9 + (dy/2+1)*3 + (dx/2+1)];
      if ((dy==-3||dy==0||dy==3) && (dx==-3||dx==0||dx==3))
        w += P.s3c[c] * P.dw3c[c*9 + (dy/3+1)*3 + (dx/3+1)];
      W[OFF_W7 + idx] = P.lepe_s[c] * w;
    }
    for (int c = tid; c < 128; c += 256){
      const float bs = P.lk_b[c] + P.b5[c] + P.b3a[c] + P.b3b[c] + P.b3c[c];
      W[OFF_BIAS + c] = P.lepe_s[c] * bs + P.lepe_b[c];
    }
    for (int i = tid; i < 512; i += 256){
      W[OFF_AVG + i] = 0.f;
      ((u32*)W + OFF_MAXU)[i] = fenc(-1e30f);
    }
  }
}

// ---------------------------------------------------------------------------
// K1: key_t[b,o,l] = bk[o] + sum_c wk[o,c]*pooled[b,c,l]. One block per (b,l).
__global__ __launch_bounds__(128) void k_key(Params P){
  __shared__ float pc[128];
  float* W = P.W;
  const int b = blockIdx.x / 49, l = blockIdx.x % 49;
  const int t = threadIdx.x;
  pc[t] = W[OFF_POOL + (size_t)(b*128+t)*49 + l];
  __syncthreads();
  float acc = P.bk[t];
  const float4* wr = (const float4*)(P.wk + t*128);
  for (int k0=0;k0<32;++k0){
    const float4 w = wr[k0];
    acc += w.x*pc[k0*4] + w.y*pc[k0*4+1] + w.z*pc[k0*4+2] + w.w*pc[k0*4+3];
  }
  W[OFF_KEY + (size_t)(b*128+t)*49 + l] = acc;
}

// ---------------------------------------------------------------------------
// K2: per-pixel pass. Fused q/v/gate 1x1 convs (48 accumulators), attention
// over 49 pooled tokens, dynamic-weight generation.
__global__ __launch_bounds__(256) void k_main(Params P){
  __shared__ float xl[128][32];   // x_skip tile (pitch 32: float4 broadcast reads)
  __shared__ float ql[128][33];   // query     (pitch 33: conflict-free o-stride writes)
  __shared__ float st[128][33];   // staging v/g
  __shared__ float attl[32][50];  // attention probs
  float* W = P.W;
  const int tid = threadIdx.x, blk = blockIdx.x;
  const int b = blk / 98;
  const int p0 = (blk % 98) * 32;

  for (int idx = tid; idx < 4096; idx += 256){
    const int c = idx >> 5, px = idx & 31;
    xl[c][px] = P.x_skip[(size_t)(b*128+c)*HW + p0 + px];
  }
  __syncthreads();

  const int o = tid & 127, g = tid >> 7;
  const int pxb = g << 4;
  float aq[16], av[16], ag[16];
  {
    const float bq_ = P.bq[o], bv_ = P.bv[o];
    #pragma unroll
    for (int j=0;j<16;++j){ aq[j]=bq_; av[j]=bv_; ag[j]=0.f; }
  }
  const float4* wqr = (const float4*)(P.wq + o*128);
  const float4* wvr = (const float4*)(P.wv + o*128);
  const float4* wgr = (const float4*)(P.gate_w + o*128);
  for (int k0 = 0; k0 < 32; ++k0){
    const float4 qw = wqr[k0], vw = wvr[k0], gw = wgr[k0];
    const float qa[4] = {qw.x,qw.y,qw.z,qw.w};
    const float va[4] = {vw.x,vw.y,vw.z,vw.w};
    const float ga[4] = {gw.x,gw.y,gw.z,gw.w};
    #pragma unroll
    for (int t=0; t<4; ++t){
      const int k = k0*4 + t;
      const float wqv = qa[t], wvv = va[t], wgv = ga[t];
      const float4 x0 = *(const float4*)&xl[k][pxb];
      const float4 x1 = *(const float4*)&xl[k][pxb+4];
      const float4 x2 = *(const float4*)&xl[k][pxb+8];
      const float4 x3 = *(const float4*)&xl[k][pxb+12];
      const float xv[16] = {x0.x,x0.y,x0.z,x0.w, x1.x,x1.y,x1.z,x1.w,
                            x2.x,x2.y,x2.z,x2.w, x3.x,x3.y,x3.z,x3.w};
      #pragma unroll
      for (int j=0;j<16;++j){
        aq[j] += wqv * xv[j];
        av[j] += wvv * xv[j];
        ag[j] += wgv * xv[j];
      }
    }
  }
  #pragma unroll
  for (int j=0;j<16;++j){ ql[o][pxb+j] = aq[j]; st[o][pxb+j] = av[j]; }
  __syncthreads();
  for (int idx = tid; idx < 4096; idx += 256){
    const int c = idx >> 5, px = idx & 31;
    W[OFF_VALUE + (size_t)(b*128+c)*HW + p0 + px] = st[c][px];
  }
  __syncthreads();
  {
    const float gs = P.gate_s[o], gb = P.gate_b[o];
    #pragma unroll
    for (int j=0;j<16;++j){
      const float y = gs*ag[j] + gb;
      st[o][pxb+j] = y / (1.f + __expf(-y));   // SiLU
    }
  }
  __syncthreads();
  for (int idx = tid; idx < 4096; idx += 256){
    const int c = idx >> 5, px = idx & 31;
    W[OFF_GATE + (size_t)(b*128+c)*HW + p0 + px] = st[c][px];
  }
  __syncthreads();

  // ---- attention over 49 tokens: 8 lanes per pixel
  const int sub = tid & 7, px = tid >> 3;
  const float* keyb = W + OFF_KEY + (size_t)b*128*49;
  float sv[7];
  #pragma unroll
  for (int j=0;j<7;++j) sv[j] = 0.f;
  for (int c=0;c<128;++c){
    const float qv = ql[c][px];
    const float* kr = keyb + c*49;
    #pragma unroll
    for (int j=0;j<7;++j){
      const int l = sub + 8*j;
      if (l < 49) sv[j] += qv * kr[l];
    }
  }
  const float scale = 0.08838834764831843f;  // 128^-0.5
  float m = -1e30f;
  #pragma unroll
  for (int j=0;j<7;++j){
    const int l = sub + 8*j;
    if (l < 49){ sv[j] *= scale; m = fmaxf(m, sv[j]); }
  }
  #pragma unroll
  for (int d=1; d<8; d<<=1) m = fmaxf(m, __shfl_xor(m, d, 64));
  float ssum = 0.f;
  float ev[7];
  #pragma unroll
  for (int j=0;j<7;++j){
    const int l = sub + 8*j;
    if (l < 49){ ev[j] = __expf(sv[j] - m); ssum += ev[j]; }
  }
  #pragma unroll
  for (int d=1; d<8; d<<=1) ssum += __shfl_xor(ssum, d, 64);
  const float inv = 1.f / ssum;
  #pragma unroll
  for (int j=0;j<7;++j){
    const int l = sub + 8*j;
    if (l < 49) attl[px][l] = ev[j] * inv;
  }
  __syncthreads();
  // dyn_w = ww @ attn + bw
  #pragma unroll
  for (int j=0;j<7;++j){
    const int oo = sub + 8*j;
    if (oo < 49){
      float a = P.bw[oo];
      const float* wr = P.ww + oo*49;
      for (int l=0;l<49;++l) a += wr[l] * attl[px][l];
      W[OFF_DYN + (size_t)(b*49+oo)*HW + p0 + px] = a;
    }
  }
}

// ---------------------------------------------------------------------------
// K3: dynamic 7x7 filter on value, fus 1x1 conv, lepe dwconv, CA partials.
__global__ __launch_bounds__(256) void k_mix(Params P){
  __shared__ float dynl[49][32];
  __shared__ float mixl[128][33];
  float* W = P.W;
  const int tid = threadIdx.x, blk = blockIdx.x;
  const int b = blk / 98, p0 = (blk % 98) * 32;
  for (int idx = tid; idx < 49*32; idx += 256){
    const int k = idx >> 5, px = idx & 31;
    dynl[k][px] = W[OFF_DYN + (size_t)(b*49+k)*HW + p0 + px];
  }
  __syncthreads();
  const int px = tid & 31, cg = tid >> 5;
  const int p = p0 + px, h = p / 56, w = p % 56;
  float acc[16];
  #pragma unroll
  for (int j=0;j<16;++j) acc[j]=0.f;
  const float* vbase = W + OFF_VALUE + (size_t)(b*128 + cg*16)*HW;
  #pragma unroll
  for (int i=0;i<7;++i){
    const int hh = h + i - 3;
    if ((unsigned)hh >= 56u) continue;
    #pragma unroll
    for (int j=0;j<7;++j){
      const int w2 = w + j - 3;
      if ((unsigned)w2 >= 56u) continue;
      const float d = dynl[i*7+j][px];
      const float* vp = vbase + hh*56 + w2;
      #pragma unroll
      for (int cc=0;cc<16;++cc) acc[cc] += d * vp[(size_t)cc*HW];
    }
  }
  #pragma unroll
  for (int cc=0;cc<16;++cc) mixl[cg*16+cc][px] = acc[cc];
  __syncthreads();
  // fus 1x1 + folded lepe bias
  float xf[16];
  #pragma unroll
  for (int cc=0;cc<16;++cc) xf[cc] = P.fus_b[cg*16+cc] + W[OFF_BIAS + cg*16+cc];
  for (int c=0;c<128;c+=4){
    float mv[4];
    #pragma unroll
    for (int q=0;q<4;++q) mv[q] = mixl[c+q][px];
    #pragma unroll
    for (int cc=0;cc<16;++cc){
      const float4 w4 = *(const float4*)(P.fus_w + (size_t)(cg*16+cc)*128 + c);
      xf[cc] += w4.x*mv[0] + w4.y*mv[1] + w4.z*mv[2] + w4.w*mv[3];
    }
  }
  // lepe: combined 7x7 depthwise on x_skip
  const float* xb0 = P.x_skip + (size_t)(b*128 + cg*16)*HW;
  const float* w7 = W + OFF_W7 + (cg*16)*49;
  #pragma unroll
  for (int i=0;i<7;++i){
    const int hh = h + i - 3;
    if ((unsigned)hh >= 56u) continue;
    #pragma unroll
    for (int j=0;j<7;++j){
      const int w2 = w + j - 3;
      if ((unsigned)w2 >= 56u) continue;
      const int off = hh*56 + w2, k = i*7 + j;
      #pragma unroll
      for (int cc=0;cc<16;++cc)
        xf[cc] += w7[cc*49 + k] * xb0[(size_t)cc*HW + off];
    }
  }
  __syncthreads();
  #pragma unroll
  for (int cc=0;cc<16;++cc) mixl[cg*16+cc][px] = xf[cc];
  __syncthreads();
  for (int idx = tid; idx < 4096; idx += 256){
    const int c = idx >> 5, pp = idx & 31;
    W[OFF_XF + (size_t)(b*128+c)*HW + p0 + pp] = mixl[c][pp];
  }
  if (tid < 128){
    float s = 0.f, mm = -1e30f;
    #pragma unroll
    for (int pp=0;pp<32;++pp){ const float v = mixl[tid][pp]; s += v; mm = fmaxf(mm, v); }
    atomicAdd(W + OFF_AVG + b*128 + tid, s);
    atomicMax((u32*)W + OFF_MAXU + b*128 + tid, fenc(mm));
  }
}

// ---------------------------------------------------------------------------
// K4: channel-attention MLP (recomputed per block, tiny) + gating epilogue.
__global__ __launch_bounds__(256) void k_final(Params P){
  __shared__ float avl[128], mxl[128], hl[16], cal[128];
  float* W = P.W;
  const int tid = threadIdx.x, blk = blockIdx.x;
  const int b = blk / 98, t0 = blk % 98;
  if (tid < 128){
    avl[tid] = W[OFF_AVG + b*128 + tid] * (1.f/3136.f);
    mxl[tid] = fdec(((u32*)W + OFF_MAXU)[b*128 + tid]);
  }
  __syncthreads();
  if (tid < 16){
    const int r = tid & 7, which = tid >> 3;
    const float* v = which ? mxl : avl;
    float a = 0.f;
    const float4* wr = (const float4*)(P.ca_w1 + r*128);
    for (int k0=0;k0<32;++k0){
      const float4 w4 = wr[k0];
      a += w4.x*v[k0*4] + w4.y*v[k0*4+1] + w4.z*v[k0*4+2] + w4.w*v[k0*4+3];
    }
    hl[tid] = fmaxf(a, 0.f);
  }
  __syncthreads();
  if (tid < 128){
    float a = 0.f;
    #pragma unroll
    for (int r=0;r<8;++r) a += P.ca_w2[tid*8+r] * (hl[r] + hl[8+r]);
    cal[tid] = 1.f/(1.f + __expf(-a));
  }
  __syncthreads();
  const float res = P.res[0];
  #pragma unroll
  for (int it=0; it<4; ++it){
    const int ofs = t0*4096 + it*1024 + tid*4;
    const int c = ofs / 3136;            // 3136 % 4 == 0 -> c constant in chunk
    const size_t gi = (size_t)b*401408 + ofs;
    const float4 gv = *(const float4*)(W + OFF_GATE + gi);
    const float4 xv = *(const float4*)(W + OFF_XF + gi);
    const float4 sk = *(const float4*)(P.x_skip + gi);
    const float ca = cal[c];
    float4 ov;
    ov.x = gv.x*xv.x*ca + sk.x*res;
    ov.y = gv.y*xv.y*ca + sk.y*res;
    ov.z = gv.z*xv.z*ca + sk.z*res;
    ov.w = gv.w*xv.w*ca + sk.w*res;
    *(float4*)(P.out + gi) = ov;
  }
}

// ---------------------------------------------------------------------------
extern "C" void kernel_launch(void* const* d_in, const int* in_sizes, int n_in,
                              void* d_out, int out_size, void* d_ws, size_t ws_size,
                              hipStream_t stream){
  Params P;
  const float* const* in = (const float* const*)d_in;
  P.x_up = in[0];  P.x_skip = in[1]; P.wq = in[2];  P.bq = in[3];
  P.wk = in[4];    P.bk = in[5];     P.wv = in[6];  P.bv = in[7];
  P.ww = in[8];    P.bw = in[9];
  P.lk_w = in[10]; P.lk_s = in[11];  P.lk_b = in[12];
  P.dw5 = in[13];  P.s5 = in[14];    P.b5 = in[15];
  P.dw3a = in[16]; P.s3a = in[17];   P.b3a = in[18];
  P.dw3b = in[19]; P.s3b = in[20];   P.b3b = in[21];
  P.dw3c = in[22]; P.s3c = in[23];   P.b3c = in[24];
  P.lepe_s = in[25]; P.lepe_b = in[26];
  P.gate_w = in[27]; P.gate_s = in[28]; P.gate_b = in[29];
  P.fus_w = in[30];  P.fus_b = in[31];
  P.ca_w1 = in[32];  P.ca_w2 = in[33]; P.res = in[34];
  P.W = (float*)d_ws;
  P.out = (float*)d_out;

  hipLaunchKernelGGL(k_prep,  dim3(33),  dim3(256), 0, stream, P);
  hipLaunchKernelGGL(k_key,   dim3(196), dim3(128), 0, stream, P);
  hipLaunchKernelGGL(k_main,  dim3(392), dim3(256), 0, stream, P);
  hipLaunchKernelGGL(k_mix,   dim3(392), dim3(256), 0, stream, P);
  hipLaunchKernelGGL(k_final, dim3(392), dim3(256), 0, stream, P);
}